// Round 10
// baseline (113.628 us; speedup 1.0000x reference)
//
#include <hip/hip_runtime.h>

// STU layer: out[b,t,e] = sum_{k,d} phi[t,k] * C[b,t,k,d] * W[k,e,d],
//            C = cumsum_t(phi[t,k] * x[b,t,d])
// Fused: out = A @ WT^T (M=16384, Kdim=4096, N=256); A-tile built in LDS from
// cumsum chains seeded by chunk-prefix states U. 8-phase schedule (m201 port):
// each K-step = 4 phases {ds_read subtile | 2 stage-gloads | 4 chain-iters |
// s_barrier | lgkmcnt(0) | setprio 8xMFMA | s_barrier}; counted vmcnt(8) once
// per step. B triple-buffered, A double-buffered, x depth-2 reg prefetch.
// B=4, T=4096, D=256, K=16, chunk CH=16.

typedef __bf16 bf16x8 __attribute__((ext_vector_type(8)));
typedef float  f32x4  __attribute__((ext_vector_type(4)));
typedef unsigned short u16;
typedef unsigned int   u32;

__device__ static inline u16 f2bf(float f) {          // RNE f32->bf16
    unsigned int u = __float_as_uint(f);
    u = (u + 0x7fffu + ((u >> 16) & 1u)) >> 16;
    return (u16)u;
}

__device__ static inline void gload16(const void* g, void* l) {
    __builtin_amdgcn_global_load_lds((const __attribute__((address_space(1))) void*)g,
                                     (__attribute__((address_space(3))) void*)l, 16, 0, 0);
}

#define SBAR()  asm volatile("s_barrier" ::: "memory")
#define LGKM0() asm volatile("s_waitcnt lgkmcnt(0)" ::: "memory")

// ---------------- k0: WT[e][d*16+k] = bf16(W[k][e][d]) ----------------
__global__ __launch_bounds__(256) void k0_wt(const float* __restrict__ W, u16* __restrict__ WT) {
    const int e = blockIdx.x, d = threadIdx.x;
    union { u16 u[16]; uint4 v[2]; } ob;
#pragma unroll
    for (int k = 0; k < 16; ++k)
        ob.u[k] = f2bf(W[((size_t)k * 256 + e) * 256 + d]);
    uint4* dst = (uint4*)(WT + (size_t)e * 4096 + d * 16);
    dst[0] = ob.v[0]; dst[1] = ob.v[1];
}

// ---------------- k1: chunk sums U[b,c,d,k] = sum_{s in 16-chunk} phi*x ----------------
__global__ __launch_bounds__(256) void k1_sums(const float* __restrict__ x,
                                               const float* __restrict__ phi,
                                               float* __restrict__ U) {
    __shared__ float phis[256];
    const int tid = threadIdx.x;
    const int b = blockIdx.x, c = blockIdx.y;
    const int t0 = c * 16;
    phis[tid] = phi[t0 * 16 + tid];
    __syncthreads();
    float acc[16];
#pragma unroll
    for (int k = 0; k < 16; ++k) acc[k] = 0.f;
    for (int s = 0; s < 16; ++s) {
        const float xv = x[(size_t)((b << 12) + t0 + s) * 256 + tid];
        union { float f[16]; float4 v[4]; } pv;
#pragma unroll
        for (int j = 0; j < 4; ++j) pv.v[j] = *(const float4*)&phis[s * 16 + j * 4];
#pragma unroll
        for (int k = 0; k < 16; ++k) acc[k] = fmaf(pv.f[k], xv, acc[k]);
    }
    float4* Up = (float4*)(U + ((size_t)((b * 256 + c) * 256 + tid)) * 16);
    union { float f[16]; float4 v[4]; } ov;
#pragma unroll
    for (int k = 0; k < 16; ++k) ov.f[k] = acc[k];
#pragma unroll
    for (int j = 0; j < 4; ++j) Up[j] = ov.v[j];
}

// ---------------- k2: exclusive scan of U over c (in place), coalesced ----------------
__global__ __launch_bounds__(256) void k2_scan(float* __restrict__ U) {
    const int b  = blockIdx.x;                     // grid (4,64)
    const int dl = threadIdx.x & 63;
    const int dk = blockIdx.y * 64 + dl;
    const int q  = threadIdx.x >> 6;               // c-quarter 0..3
    float* base = U + (size_t)b * 1048576 + (size_t)(q * 64) * 4096 + dk;
    float s = 0.f;
#pragma unroll 8
    for (int j = 0; j < 64; ++j) s += base[(size_t)j * 4096];
    __shared__ float qs[4][64];
    qs[q][dl] = s;
    __syncthreads();
    float pre = 0.f;
#pragma unroll
    for (int i = 0; i < 4; ++i) pre += (i < q) ? qs[i][dl] : 0.f;
    float run = pre;
#pragma unroll 8
    for (int j = 0; j < 64; ++j) {
        const float v = base[(size_t)j * 4096];
        base[(size_t)j * 4096] = run;
        run += v;
    }
}

// ---------------- k4: fused A-build + GEMM, 8-phase, ks-split=2 ----------------
// BM=128, BN=256, BK=64, 32 K-steps, 512 thr = 8 waves (2M x 4N, 64x64 tiles).
// Waves 0-3: chain-build (2 chains/lane, 4 s-iters per phase).
// Waves 4-7: B staging (2 gload16 per phase). All: 8 MFMA per phase.
// LDS 128KB: B[3][32768] @0, A[2][16384] @98304.
__global__ __launch_bounds__(512, 2) void k4_fused(const float* __restrict__ x,
                                                   const float* __restrict__ phi,
                                                   const float* __restrict__ U,
                                                   const u16* __restrict__ BT,
                                                   float* __restrict__ C) {
    __shared__ __align__(16) char smem[131072];
    const int tid = threadIdx.x;
    const int m0 = blockIdx.x * 128;             // global row base (bt)
    const int ks = blockIdx.y;                   // kdim half 0/1
    const int b  = m0 >> 12, t0 = m0 & 4095, c0 = t0 >> 4;
    const int w = tid >> 6, l = tid & 63;
    const int wm = (w >> 2) * 64, wn = (w & 3) * 64;
    const int lg = l >> 4, lr = l & 15;
    f32x4 acc[4][4] = {};

    const bool is_chain = (w < 4);
    const bool is_stage = (w >= 4);

    // chain lane mapping: lane owns chains (ch, dl, k=2kp,2kp+1)
    const int kp = l & 7, dl = (l >> 3) & 3, ch = (w << 1) | (l >> 5);  // ch 0..7
    const int colb = dl * 32 + kp * 4;
    float2 p01[16];
    if (is_chain) {
#pragma unroll
        for (int s = 0; s < 16; ++s)
            p01[s] = *(const float2*)&phi[(t0 + ch * 16 + s) * 16 + kp * 2];
    }

    const int tl = tid & 255;
    const char* bsrc = (const char*)BT + (size_t)(tl >> 3) * 8192 + ks * 4096
                     + (((tl & 7) * 16) ^ (((tl >> 3) & 7) << 4));
    char* const smemA = smem + 98304;

    auto issueX = [&](float (&xr)[16], float2& us, int kt) {
        const int d = ks * 128 + kt * 4 + dl;
        const float* xp = x + (size_t)(m0 + ch * 16) * 256 + d;
#pragma unroll
        for (int s = 0; s < 16; ++s) xr[s] = xp[(size_t)s * 256];
        us = *(const float2*)&U[((size_t)((b * 256 + c0 + ch) * 256 + d)) * 16 + kp * 2];
    };

    bf16x8 bfv[4], af0, af1;
    auto rdB = [&](const char* Bbase, int kk) {
        const int kb = kk * 64 + lg * 16;
#pragma unroll
        for (int ni = 0; ni < 4; ++ni) {
            const int n = wn + ni * 16 + lr;
            bfv[ni] = *(const bf16x8*)(Bbase + n * 128 + (kb ^ ((n & 7) << 4)));
        }
    };
    auto rdA = [&](const char* Abase, int kk, int mh) {
        const int kb = kk * 64 + lg * 16;
        const int ra = wm + mh * 32 + lr, rb = ra + 16;
        af0 = *(const bf16x8*)(Abase + ra * 128 + (kb ^ ((ra & 7) << 4)));
        af1 = *(const bf16x8*)(Abase + rb * 128 + (kb ^ ((rb & 7) << 4)));
    };
    auto mm8 = [&](int mh) {
        __builtin_amdgcn_s_setprio(1);
#pragma unroll
        for (int ni = 0; ni < 4; ++ni)
            acc[mh * 2][ni] = __builtin_amdgcn_mfma_f32_16x16x32_bf16(af0, bfv[ni], acc[mh * 2][ni], 0, 0, 0);
#pragma unroll
        for (int ni = 0; ni < 4; ++ni)
            acc[mh * 2 + 1][ni] = __builtin_amdgcn_mfma_f32_16x16x32_bf16(af1, bfv[ni], acc[mh * 2 + 1][ni], 0, 0, 0);
        __builtin_amdgcn_s_setprio(0);
    };

    int br = 0, bw = 2;

    auto body = [&](int kt, float (&xW)[16], float2& uW,
                    const float (&xR)[16], float2 uR) {
        const int abr = kt & 1;
        const char* Abase = smemA + abr * 16384;
        const char* Bbase = smem + br * 32768;
        char* Ab = smemA + (abr ^ 1) * 16384 + ch * 2048;
        const bool doCh = is_chain && (kt + 1 < 32);
        const bool doIs = (kt + 2 < 32);
        float r0 = 0.f, r1 = 0.f;
        if (doCh) { r0 = uR.x; r1 = uR.y; }

        auto slice = [&](int q) {
#pragma unroll
            for (int j = 0; j < 4; ++j) {
                const int s = q * 4 + j;
                r0 = fmaf(p01[s].x, xR[s], r0);
                r1 = fmaf(p01[s].y, xR[s], r1);
                const float v0 = p01[s].x * r0, v1 = p01[s].y * r1;
                u32 pk;
                asm("v_cvt_pk_bf16_f32 %0, %1, %2" : "=v"(pk) : "v"(v0), "v"(v1));
                *(u32*)(Ab + s * 128 + (colb ^ ((s & 7) << 4))) = pk;
            }
        };
        auto sg = [&](int q) {                   // stage slice: 2 gloads of tile kt+2
            char* dst = smem + bw * 32768 + tl * 16;
            const char* src = bsrc + (size_t)(kt + 2) * 128;
            gload16(src + (size_t)(2 * q) * 262144,     dst + (2 * q) * 4096);
            gload16(src + (size_t)(2 * q + 1) * 262144, dst + (2 * q + 1) * 4096);
        };

        // ---- phase 0: kk0, mi 0-1
        rdB(Bbase, 0); rdA(Abase, 0, 0);
        if (is_stage && doIs) sg(0);
        if (doCh) slice(0);
        SBAR(); LGKM0();
        mm8(0);
        SBAR();
        // ---- phase 1: kk0, mi 2-3
        rdA(Abase, 0, 1);
        if (is_stage && doIs) sg(1);
        if (is_chain && doIs) issueX(xW, uW, kt + 2);
        if (doCh) slice(1);
        SBAR(); LGKM0();
        mm8(1);
        SBAR();
        // ---- phase 2: kk1, mi 0-1
        rdB(Bbase, 1); rdA(Abase, 1, 0);
        if (is_stage && doIs) sg(2);
        if (doCh) slice(2);
        SBAR(); LGKM0();
        mm8(0);
        SBAR();
        // ---- phase 3: kk1, mi 2-3
        rdA(Abase, 1, 1);
        if (is_stage && doIs) sg(3);
        if (doCh) slice(3);
        if (is_chain) LGKM0();                   // drain A(kt+1) writes
        SBAR(); LGKM0();
        mm8(1);
        if (is_stage) {
            if (doIs) asm volatile("s_waitcnt vmcnt(8)" ::: "memory");
            else      asm volatile("s_waitcnt vmcnt(0)" ::: "memory");
        }
        if (kt < 31) SBAR();
        br = (br == 2) ? 0 : br + 1;
        bw = (bw == 2) ? 0 : bw + 1;
    };

    // ---- prologue: B(0),B(1) in flight; x(0),x(1) in regs; A(0) built
    float xA[16], xB[16]; float2 uA, uB;
    if (is_chain) { issueX(xA, uA, 0); issueX(xB, uB, 1); }
    if (is_stage) {
#pragma unroll
        for (int c = 0; c < 8; ++c) {
            gload16(bsrc + (size_t)c * 262144,        smem + tl * 16 + c * 4096);
        }
#pragma unroll
        for (int c = 0; c < 8; ++c) {
            gload16(bsrc + 128 + (size_t)c * 262144,  smem + 32768 + tl * 16 + c * 4096);
        }
    }
    __builtin_amdgcn_sched_barrier(0);
    if (is_chain) {
        float r0 = uA.x, r1 = uA.y;
        char* Ab0 = smemA + ch * 2048;
#pragma unroll
        for (int s = 0; s < 16; ++s) {
            r0 = fmaf(p01[s].x, xA[s], r0);
            r1 = fmaf(p01[s].y, xA[s], r1);
            const float v0 = p01[s].x * r0, v1 = p01[s].y * r1;
            u32 pk;
            asm("v_cvt_pk_bf16_f32 %0, %1, %2" : "=v"(pk) : "v"(v0), "v"(v1));
            *(u32*)(Ab0 + s * 128 + (colb ^ ((s & 7) << 4))) = pk;
        }
        LGKM0();
    }
    if (is_stage) asm volatile("s_waitcnt vmcnt(8)" ::: "memory");  // B(0) landed
    SBAR();

    for (int kt = 0; kt < 32; kt += 2) {
        body(kt,     xA, uA, xB, uB);            // even: write xA, read xB
        body(kt + 1, xB, uB, xA, uA);            // odd : write xB, read xA
    }

    // ---- epilogue: two contributions per element (ks=0/1), commutative f32 adds
#pragma unroll
    for (int mi = 0; mi < 4; ++mi)
#pragma unroll
        for (int ni = 0; ni < 4; ++ni)
#pragma unroll
            for (int r = 0; r < 4; ++r) {
                const int row = m0 + wm + mi * 16 + lg * 4 + r;
                const int col = wn + ni * 16 + lr;
                unsafeAtomicAdd(&C[(size_t)row * 256 + col], acc[mi][ni][r]);
            }
}

extern "C" void kernel_launch(void* const* d_in, const int* in_sizes, int n_in,
                              void* d_out, int out_size, void* d_ws, size_t ws_size,
                              hipStream_t stream) {
    const float* x   = (const float*)d_in[0];   // (4,4096,256)
    const float* W   = (const float*)d_in[1];   // (16,256,256)
    const float* phi = (const float*)d_in[2];   // (4096,16)
    float* out = (float*)d_out;                 // (4,4096,256) f32

    char* ws = (char*)d_ws;
    u16*   WT = (u16*)ws;                       // 2 MB
    float* U  = (float*)(ws + (2u << 20));      // 16 MB

    k0_wt  <<<256, 256, 0, stream>>>(W, WT);
    k1_sums<<<dim3(4, 256), 256, 0, stream>>>(x, phi, U);
    k2_scan<<<dim3(4, 64), 256, 0, stream>>>(U);
    hipMemsetAsync(d_out, 0, (size_t)out_size * sizeof(float), stream);
    k4_fused<<<dim3(128, 2), 512, 0, stream>>>(x, phi, U, WT, out);
}